// Round 8
// baseline (416.016 us; speedup 1.0000x reference)
//
#include <hip/hip_runtime.h>

// ---------------- problem constants ----------------
#define BATCH   4096
#define N_REL   500
#define D1      200
#define W_IN    400          // 2*D1
#define OC      32
#define FW      9
#define W_OUT   392          // W_IN - FW + 1
#define FC_LEN  12544        // OC * W_OUT
#define FC1_LEN 288          // OC * FW
#define NDIM    400          // fc output dim
#define KDIM    FC_LEN
#define EPS     1e-5f

// ---------------- GEMM tiling ----------------
#define TM      128
#define TN      128
#define BK      64
#define SKA     7            // split-K for async path: KCH = 1792 = 28*64
#define KCHA    (KDIM / SKA)
#define KITA    (KCHA / BK)

typedef __attribute__((ext_vector_type(8))) __bf16 bf16x8;
typedef __attribute__((ext_vector_type(4))) float  f32x4;

// async global->LDS, 16B per lane; LDS dest = wave-uniform base + lane*16  [m97/m104]
__device__ __forceinline__ void gld_lds16(const void* g, void* l) {
    __builtin_amdgcn_global_load_lds(
        (const __attribute__((address_space(1))) void*)g,
        (__attribute__((address_space(3))) void*)l,
        16, 0, 0);
}

// ============ kernel 0: fc_w fp32 -> bf16 ============
__global__ __launch_bounds__(256)
void cvt_w(const float* __restrict__ src, __bf16* __restrict__ dst)
{
    const int i = (blockIdx.x * 256 + threadIdx.x) * 8;   // 2450 blocks cover 5,017,600 exactly
    float4 a = *(const float4*)(src + i);
    float4 b = *(const float4*)(src + i + 4);
    bf16x8 o;
    o[0] = (__bf16)a.x; o[1] = (__bf16)a.y; o[2] = (__bf16)a.z; o[3] = (__bf16)a.w;
    o[4] = (__bf16)b.x; o[5] = (__bf16)b.y; o[6] = (__bf16)b.z; o[7] = (__bf16)b.w;
    *(bf16x8*)(dst + i) = o;
}

// ============ kernel A: per-relation hypernet filters, bn1 scale folded ============
__global__ __launch_bounds__(320)
void krel(const float* __restrict__ R, const float* __restrict__ fc1w,
          const float* __restrict__ fc1b,
          const float* __restrict__ g1, const float* __restrict__ v1,
          float* __restrict__ KR)
{
    __shared__ float rs[D1];
    const int rel = blockIdx.x;
    const int t = threadIdx.x;
    if (t < D1) rs[t] = R[(size_t)rel * D1 + t];
    __syncthreads();
    if (t < FC1_LEN) {
        const float4* wrow = (const float4*)(fc1w + (size_t)t * D1);
        float acc = fc1b[t];
        #pragma unroll 10
        for (int c = 0; c < D1 / 4; ++c) {
            float4 wv = wrow[c];
            acc += rs[c * 4 + 0] * wv.x + rs[c * 4 + 1] * wv.y
                 + rs[c * 4 + 2] * wv.z + rs[c * 4 + 3] * wv.w;
        }
        const int oc = t / FW;
        KR[(size_t)rel * FC1_LEN + t] = acc * (g1[oc] * rsqrtf(v1[oc] + EPS));
    }
}

// ============ kernel B: gather + bn0 + conv(1x9) + bn1 -> flat (bf16) ============
// x window read DIRECTLY from E rows (L1-resident), bn0 on the fly; no xs LDS.
__global__ __launch_bounds__(256)
void conv_flat(const int* __restrict__ e1i, const int* __restrict__ ri,
               const int* __restrict__ e2i,
               const float* __restrict__ E, const float* __restrict__ KR,
               const float* __restrict__ g0, const float* __restrict__ b0,
               const float* __restrict__ m0p, const float* __restrict__ v0,
               const float* __restrict__ g1, const float* __restrict__ b1,
               const float* __restrict__ m1, const float* __restrict__ v1,
               __bf16* __restrict__ flat)
{
    __shared__ float ks[FC1_LEN];
    __shared__ float cadd[OC];

    const int b = blockIdx.x;
    const int t = threadIdx.x;
    const int i1 = e1i[b], i2 = e2i[b], ir = ri[b];

    const float s0 = g0[0] * rsqrtf(v0[0] + EPS);
    const float t0 = b0[0] - m0p[0] * s0;
    const float* p1 = E + (size_t)i1 * D1;
    const float* p2 = E + (size_t)i2 * D1;

    if (t >= 224 && t < 224 + OC) {
        const int oc = t - 224;
        cadd[oc] = b1[oc] - m1[oc] * (g1[oc] * rsqrtf(v1[oc] + EPS));
    }
    for (int i = t; i < FC1_LEN; i += 256)
        ks[i] = KR[(size_t)ir * FC1_LEN + i];
    __syncthreads();

    const size_t obase = (size_t)b * FC_LEN;
    for (int u = t; u < OC * 49; u += 256) {        // 1568 units: 8 outputs each
        const int oc = u / 49;
        const int w  = (u - oc * 49) * 8;
        float4 q0, q1, q2, q3;
        if (w <= 184) {                  // window [w, w+15] entirely in e1
            q0 = *(const float4*)(p1 + w);     q1 = *(const float4*)(p1 + w + 4);
            q2 = *(const float4*)(p1 + w + 8); q3 = *(const float4*)(p1 + w + 12);
        } else if (w >= 200) {           // entirely in e2
            const float* p = p2 + (w - 200);
            q0 = *(const float4*)(p);     q1 = *(const float4*)(p + 4);
            q2 = *(const float4*)(p + 8); q3 = *(const float4*)(p + 12);
        } else {                         // w == 192: straddles the concat boundary
            q0 = *(const float4*)(p1 + 192); q1 = *(const float4*)(p1 + 196);
            q2 = *(const float4*)(p2);       q3 = *(const float4*)(p2 + 4);
        }
        float x[16] = {q0.x, q0.y, q0.z, q0.w, q1.x, q1.y, q1.z, q1.w,
                       q2.x, q2.y, q2.z, q2.w, q3.x, q3.y, q3.z, q3.w};
        #pragma unroll
        for (int p = 0; p < 16; ++p) x[p] = x[p] * s0 + t0;   // bn0

        const float c0 = cadd[oc];
        float a[8] = {c0, c0, c0, c0, c0, c0, c0, c0};
        #pragma unroll
        for (int j = 0; j < FW; ++j) {
            const float kj = ks[oc * FW + j];                 // broadcast (free)
            #pragma unroll
            for (int p = 0; p < 8; ++p) a[p] += x[j + p] * kj;
        }
        bf16x8 o;
        #pragma unroll
        for (int p = 0; p < 8; ++p) o[p] = (__bf16)a[p];
        *(bf16x8*)(flat + obase + oc * W_OUT + w) = o;        // 16B aligned, coalesced
    }
}

// ============ kernel 2a: async MFMA GEMM, BK=64, 8-slot XOR swizzle, split-K 7 ============
// LDS tile row = 128B (8 x 16B slots); slot s of row r holds global k-chunk s^(r&7).
__global__ __launch_bounds__(256, 3)
void gemm_async(const __bf16* __restrict__ A, const __bf16* __restrict__ B,
                float* __restrict__ Hpart)
{
    __shared__ __align__(16) __bf16 Asm[TM * BK];   // 16 KB
    __shared__ __align__(16) __bf16 Bsm[TN * BK];   // 16 KB

    const int tid  = threadIdx.x;
    const int wave = tid >> 6;
    const int lane = tid & 63;
    const int m0 = blockIdx.x * TM;
    const int n0 = blockIdx.y * TN;
    const size_t kbase = (size_t)blockIdx.z * KCHA;

    // staging: 1024 16B-chunks per tile, 4 phases; chunk = p*256 + tid
    // row = p*32 + (tid>>3), slot = tid&7; source k-chunk = slot ^ (row&7)
    const int subsw = (tid & 7) ^ ((tid >> 3) & 7);
    const __bf16* ag[4]; const __bf16* bg[4];
    __bf16* al[4]; __bf16* bl[4];
    #pragma unroll
    for (int p = 0; p < 4; ++p) {
        const int row = p * 32 + (tid >> 3);
        ag[p] = A + (size_t)(m0 + row) * KDIM + kbase + subsw * 8;
        int rg = n0 + row; if (rg > NDIM - 1) rg = NDIM - 1;   // clamp padded rows
        bg[p] = B + (size_t)rg * KDIM + kbase + subsw * 8;
        al[p] = Asm + p * 2048 + tid * 8;                      // = wave-uniform + lane*16B
        bl[p] = Bsm + p * 2048 + tid * 8;
    }

    const int quad = lane >> 4;
    const int mrow = lane & 15;
    const int m7   = mrow & 7;
    const int wm = wave >> 1, wn = wave & 1;    // 2x2 wave grid, 64x64 per wave
    int rowoff_a[4], rowoff_b[4];
    #pragma unroll
    for (int t = 0; t < 4; ++t) {
        rowoff_a[t] = (wm * 64 + t * 16 + mrow) * BK;
        rowoff_b[t] = (wn * 64 + t * 16 + mrow) * BK;
    }

    f32x4 acc[4][4];
    #pragma unroll
    for (int i = 0; i < 4; ++i)
        #pragma unroll
        for (int j = 0; j < 4; ++j) acc[i][j] = (f32x4){0.f, 0.f, 0.f, 0.f};

    for (int it = 0; it < KITA; ++it) {
        #pragma unroll
        for (int p = 0; p < 4; ++p) {
            gld_lds16(ag[p], al[p]);
            gld_lds16(bg[p], bl[p]);
            ag[p] += BK; bg[p] += BK;
        }
        __syncthreads();   // vmcnt drained -> LDS valid

        #pragma unroll
        for (int kk = 0; kk < 2; ++kk) {
            const int sl = ((kk * 4 + quad) ^ m7) * 8;   // un-swizzle slot
            bf16x8 av[4], bv[4];
            #pragma unroll
            for (int t = 0; t < 4; ++t) av[t] = *(const bf16x8*)(Asm + rowoff_a[t] + sl);
            #pragma unroll
            for (int t = 0; t < 4; ++t) bv[t] = *(const bf16x8*)(Bsm + rowoff_b[t] + sl);
            #pragma unroll
            for (int i = 0; i < 4; ++i)
                #pragma unroll
                for (int j = 0; j < 4; ++j)
                    acc[i][j] = __builtin_amdgcn_mfma_f32_16x16x32_bf16(av[i], bv[j], acc[i][j], 0, 0, 0);
        }
        __syncthreads();   // reads done before next stage overwrites
    }

    // epilogue: C/D layout col=lane&15, row=(lane>>4)*4+reg  [m89]
    float* Hp = Hpart + (size_t)blockIdx.z * BATCH * NDIM;
    #pragma unroll
    for (int i = 0; i < 4; ++i) {
        const int rbase = m0 + wm * 64 + i * 16 + quad * 4;
        #pragma unroll
        for (int j = 0; j < 4; ++j) {
            const int col = n0 + wn * 64 + j * 16 + mrow;
            if (col < NDIM) {
                #pragma unroll
                for (int r = 0; r < 4; ++r)
                    Hp[(size_t)(rbase + r) * NDIM + col] = acc[i][j][r];
            }
        }
    }
}

// ============ kernel 2b: proven fallback (VGPR staging, fp32 B, split-K 4, BK=32) ============
__global__ __launch_bounds__(256, 2)
void gemm_bt(const __bf16* __restrict__ Aflat, const float* __restrict__ Bwf,
             float* __restrict__ Hpart)
{
    __shared__ __align__(16) __bf16 Asm[TM * 32];
    __shared__ __align__(16) __bf16 Bsm[TN * 32];

    const int tid  = threadIdx.x;
    const int wave = tid >> 6;
    const int lane = tid & 63;
    const int m0 = blockIdx.x * TM;
    const int n0 = blockIdx.y * TN;
    const size_t kbase = (size_t)blockIdx.z * (KDIM / 4);

    const int row0 = tid >> 2, sub = tid & 3;
    const int row1 = 64 + row0;
    const __bf16* ag0 = Aflat + (size_t)(m0 + row0) * KDIM + kbase + sub * 8;
    const __bf16* ag1 = Aflat + (size_t)(m0 + row1) * KDIM + kbase + sub * 8;
    int rg0 = n0 + row0; if (rg0 > NDIM - 1) rg0 = NDIM - 1;
    int rg1 = n0 + row1; if (rg1 > NDIM - 1) rg1 = NDIM - 1;
    const float* bg0 = Bwf + (size_t)rg0 * KDIM + kbase + sub * 8;
    const float* bg1 = Bwf + (size_t)rg1 * KDIM + kbase + sub * 8;
    __bf16* la0 = Asm + tid * 8;
    __bf16* la1 = Asm + 2048 + tid * 8;
    __bf16* lb0 = Bsm + tid * 8;
    __bf16* lb1 = Bsm + 2048 + tid * 8;

    const int quad = lane >> 4;
    const int mrow = lane & 15;
    const int wm = wave >> 1, wn = wave & 1;
    const __bf16* afr[4]; const __bf16* bfr[4];
    #pragma unroll
    for (int t = 0; t < 4; ++t) {
        afr[t] = Asm + (wm * 64 + t * 16 + mrow) * 32 + quad * 8;
        bfr[t] = Bsm + (wn * 64 + t * 16 + mrow) * 32 + quad * 8;
    }

    f32x4 acc[4][4];
    #pragma unroll
    for (int i = 0; i < 4; ++i)
        #pragma unroll
        for (int j = 0; j < 4; ++j) acc[i][j] = (f32x4){0.f, 0.f, 0.f, 0.f};

    for (int it = 0; it < (KDIM / 4) / 32; ++it) {
        bf16x8 ra0 = *(const bf16x8*)ag0;
        bf16x8 ra1 = *(const bf16x8*)ag1;
        float4 b0a = *(const float4*)bg0;
        float4 b0b = *(const float4*)(bg0 + 4);
        float4 b1a = *(const float4*)bg1;
        float4 b1b = *(const float4*)(bg1 + 4);
        ag0 += 32; ag1 += 32; bg0 += 32; bg1 += 32;

        bf16x8 rb0, rb1;
        rb0[0] = (__bf16)b0a.x; rb0[1] = (__bf16)b0a.y; rb0[2] = (__bf16)b0a.z; rb0[3] = (__bf16)b0a.w;
        rb0[4] = (__bf16)b0b.x; rb0[5] = (__bf16)b0b.y; rb0[6] = (__bf16)b0b.z; rb0[7] = (__bf16)b0b.w;
        rb1[0] = (__bf16)b1a.x; rb1[1] = (__bf16)b1a.y; rb1[2] = (__bf16)b1a.z; rb1[3] = (__bf16)b1a.w;
        rb1[4] = (__bf16)b1b.x; rb1[5] = (__bf16)b1b.y; rb1[6] = (__bf16)b1b.z; rb1[7] = (__bf16)b1b.w;

        __syncthreads();
        *(bf16x8*)la0 = ra0;
        *(bf16x8*)la1 = ra1;
        *(bf16x8*)lb0 = rb0;
        *(bf16x8*)lb1 = rb1;
        __syncthreads();

        bf16x8 av[4], bv[4];
        #pragma unroll
        for (int t = 0; t < 4; ++t) av[t] = *(const bf16x8*)afr[t];
        #pragma unroll
        for (int t = 0; t < 4; ++t) bv[t] = *(const bf16x8*)bfr[t];
        #pragma unroll
        for (int i = 0; i < 4; ++i)
            #pragma unroll
            for (int j = 0; j < 4; ++j)
                acc[i][j] = __builtin_amdgcn_mfma_f32_16x16x32_bf16(av[i], bv[j], acc[i][j], 0, 0, 0);
    }

    float* Hp = Hpart + (size_t)blockIdx.z * BATCH * NDIM;
    #pragma unroll
    for (int i = 0; i < 4; ++i) {
        const int rbase = m0 + wm * 64 + i * 16 + quad * 4;
        #pragma unroll
        for (int j = 0; j < 4; ++j) {
            const int col = n0 + wn * 64 + j * 16 + mrow;
            if (col < NDIM) {
                #pragma unroll
                for (int r = 0; r < 4; ++r)
                    Hp[(size_t)(rbase + r) * NDIM + col] = acc[i][j][r];
            }
        }
    }
}

// ============ kernel 3: sum partials + fc_b + bn2 + fc2 dot + tanh + bias ============
__global__ __launch_bounds__(256)
void finalize(const float* __restrict__ Hpart, int sk,
              const float* __restrict__ fcb,
              const float* __restrict__ g2, const float* __restrict__ b2,
              const float* __restrict__ m2, const float* __restrict__ v2,
              const float* __restrict__ fc2w, const float* __restrict__ fc2b,
              const float* __restrict__ bias,
              float* __restrict__ out)
{
    const int wave = threadIdx.x >> 6, lane = threadIdx.x & 63;
    const int e = blockIdx.x * 4 + wave;

    float acc = 0.f;
    for (int o = lane; o < NDIM; o += 64) {
        float hv = 0.f;
        for (int z = 0; z < sk; ++z)
            hv += Hpart[(size_t)z * BATCH * NDIM + (size_t)e * NDIM + o];
        hv += fcb[o];
        const float s2 = g2[o] * rsqrtf(v2[o] + EPS);
        const float hb = (hv - m2[o]) * s2 + b2[o];
        acc += hb * fc2w[o];
    }
    #pragma unroll
    for (int off = 32; off > 0; off >>= 1) acc += __shfl_down(acc, off);
    if (lane == 0)
        out[e] = tanhf(acc + fc2b[0]) + bias[0];
}

extern "C" void kernel_launch(void* const* d_in, const int* in_sizes, int n_in,
                              void* d_out, int out_size, void* d_ws, size_t ws_size,
                              hipStream_t stream)
{
    const int*   e1i  = (const int*)d_in[0];
    const int*   ri   = (const int*)d_in[1];
    const int*   e2i  = (const int*)d_in[2];
    const float* E    = (const float*)d_in[3];
    const float* R    = (const float*)d_in[4];
    const float* g0   = (const float*)d_in[5];
    const float* b0   = (const float*)d_in[6];
    const float* m0p  = (const float*)d_in[7];
    const float* v0   = (const float*)d_in[8];
    const float* fc1w = (const float*)d_in[9];
    const float* fc1b = (const float*)d_in[10];
    const float* g1   = (const float*)d_in[11];
    const float* b1   = (const float*)d_in[12];
    const float* m1   = (const float*)d_in[13];
    const float* v1   = (const float*)d_in[14];
    const float* fcw  = (const float*)d_in[15];
    const float* fcb  = (const float*)d_in[16];
    const float* g2   = (const float*)d_in[17];
    const float* b2   = (const float*)d_in[18];
    const float* m2   = (const float*)d_in[19];
    const float* v2   = (const float*)d_in[20];
    const float* fc2w = (const float*)d_in[21];
    const float* fc2b = (const float*)d_in[22];
    const float* bias = (const float*)d_in[23];

    const size_t flat_b = (size_t)BATCH * FC_LEN * 2;   // 102,760,448
    const size_t bw_b   = (size_t)NDIM * KDIM * 2;      //  10,035,200
    const size_t hp_b1  = (size_t)BATCH * NDIM * 4;     //   6,553,600 per split
    const size_t kr_b   = (size_t)N_REL * FC1_LEN * 4;  //     576,000
    const size_t need7  = flat_b + bw_b + SKA * hp_b1 + kr_b;   // ~159.2 MB (ws>=165.8 proven R7)

    __bf16* flat = (__bf16*)d_ws;

    if (ws_size >= need7) {
        __bf16* Bw    = (__bf16*)((char*)d_ws + flat_b);
        float*  Hpart = (float*)((char*)d_ws + flat_b + bw_b);
        float*  KR    = (float*)((char*)d_ws + flat_b + bw_b + (size_t)SKA * hp_b1);

        krel<<<N_REL, 320, 0, stream>>>(R, fc1w, fc1b, g1, v1, KR);
        conv_flat<<<BATCH, 256, 0, stream>>>(e1i, ri, e2i, E, KR, g0, b0, m0p, v0,
                                             g1, b1, m1, v1, flat);
        cvt_w<<<(NDIM * KDIM) / 2048, 256, 0, stream>>>(fcw, Bw);

        dim3 grid(BATCH / TM, (NDIM + TN - 1) / TN, SKA);   // 32 x 4 x 7
        gemm_async<<<grid, 256, 0, stream>>>(flat, Bw, Hpart);

        finalize<<<BATCH / 4, 256, 0, stream>>>(Hpart, SKA, fcb, g2, b2, m2, v2,
                                                fc2w, fc2b, bias, (float*)d_out);
    } else {
        // fallback: no Bw; split-K 4; KR after Hpart
        float*  Hpart = (float*)((char*)d_ws + flat_b);
        float*  KR    = (float*)((char*)d_ws + flat_b + 4 * hp_b1);

        krel<<<N_REL, 320, 0, stream>>>(R, fc1w, fc1b, g1, v1, KR);
        conv_flat<<<BATCH, 256, 0, stream>>>(e1i, ri, e2i, E, KR, g0, b0, m0p, v0,
                                             g1, b1, m1, v1, flat);

        dim3 grid(BATCH / TM, (NDIM + TN - 1) / TN, 4);
        gemm_bt<<<grid, 256, 0, stream>>>(flat, fcw, Hpart);
        finalize<<<BATCH / 4, 256, 0, stream>>>(Hpart, 4, fcb, g2, b2, m2, v2,
                                                fc2w, fc2b, bias, (float*)d_out);
    }
}

// Round 9
// 318.761 us; speedup vs baseline: 1.3051x; 1.3051x over previous
//
#include <hip/hip_runtime.h>

// ---------------- problem constants ----------------
#define BATCH   4096
#define N_REL   500
#define D1      200
#define W_IN    400          // 2*D1
#define OC      32
#define FW      9
#define W_OUT   392          // W_IN - FW + 1
#define FC_LEN  12544        // OC * W_OUT
#define FC1_LEN 288          // OC * FW
#define NDIM    400          // fc output dim
#define KDIM    FC_LEN
#define EPS     1e-5f

// ---------------- GEMM tiling (R7-proven: BK=32, split-K 8, 4 blocks/CU) ----------------
#define TM      128
#define TN      128
#define BK      32
#define SKA     8
#define KCHA    (KDIM / SKA)    // 1568
#define KITA    (KCHA / BK)     // 49

#define CVT_BLOCKS ((NDIM * KDIM) / 2048)   // 2450

typedef __attribute__((ext_vector_type(8))) __bf16 bf16x8;
typedef __attribute__((ext_vector_type(4))) float  f32x4;

// async global->LDS, 16B per lane; LDS dest = wave-uniform base + lane*16  [m97/m104]
__device__ __forceinline__ void gld_lds16(const void* g, void* l) {
    __builtin_amdgcn_global_load_lds(
        (const __attribute__((address_space(1))) void*)g,
        (__attribute__((address_space(3))) void*)l,
        16, 0, 0);
}

// ============ kernel 1: [blocks 0..4095] gather + bn0 + hypernet + conv + bn1 -> flat
//              [blocks 4096..6545] fc_w fp32 -> bf16 (fused to save a launch gap ~25us) ====
__global__ __launch_bounds__(256)
void prep_conv_cvt(const int* __restrict__ e1i, const int* __restrict__ ri,
                   const int* __restrict__ e2i,
                   const float* __restrict__ E, const float* __restrict__ R,
                   const float* __restrict__ g0, const float* __restrict__ b0,
                   const float* __restrict__ m0p, const float* __restrict__ v0,
                   const float* __restrict__ fc1w, const float* __restrict__ fc1b,
                   const float* __restrict__ g1, const float* __restrict__ b1,
                   const float* __restrict__ m1, const float* __restrict__ v1,
                   const float* __restrict__ fcw,
                   __bf16* __restrict__ flat, __bf16* __restrict__ Bw)
{
    const int bid = blockIdx.x;
    const int t = threadIdx.x;

    if (bid >= BATCH) {                    // ---- cvt_w part ----
        const int i = ((bid - BATCH) * 256 + t) * 8;
        float4 a = *(const float4*)(fcw + i);
        float4 b = *(const float4*)(fcw + i + 4);
        bf16x8 o;
        o[0] = (__bf16)a.x; o[1] = (__bf16)a.y; o[2] = (__bf16)a.z; o[3] = (__bf16)a.w;
        o[4] = (__bf16)b.x; o[5] = (__bf16)b.y; o[6] = (__bf16)b.z; o[7] = (__bf16)b.w;
        *(bf16x8*)(Bw + i) = o;
        return;
    }

    // ---- prep part (R6-proven structure, bn1 folded into ks/cadd) ----
    __shared__ float xs[W_IN];
    __shared__ float rs[D1];
    __shared__ float ks[FC1_LEN];
    __shared__ float cadd[OC];

    const int b = bid;
    const int i1 = e1i[b], i2 = e2i[b], ir = ri[b];

    const float s0 = g0[0] * rsqrtf(v0[0] + EPS);
    const float t0 = b0[0] - m0p[0] * s0;

    if (t < D1) {
        xs[t]      = E[(size_t)i1 * D1 + t] * s0 + t0;
        xs[D1 + t] = E[(size_t)i2 * D1 + t] * s0 + t0;
        rs[t]      = R[(size_t)ir * D1 + t];
    }
    if (t >= 224 && t < 224 + OC) {
        const int oc = t - 224;
        cadd[oc] = b1[oc] - m1[oc] * (g1[oc] * rsqrtf(v1[oc] + EPS));
    }
    __syncthreads();

    // ks[i] = (rs . fc1w[i] + fc1b[i]) * inv1[i/9]
    for (int i = t; i < FC1_LEN; i += 256) {
        const float4* wrow = (const float4*)(fc1w + (size_t)i * D1);
        float acc = fc1b[i];
        #pragma unroll 10
        for (int c = 0; c < D1 / 4; ++c) {
            float4 wv = wrow[c];
            acc += rs[c * 4 + 0] * wv.x + rs[c * 4 + 1] * wv.y
                 + rs[c * 4 + 2] * wv.z + rs[c * 4 + 3] * wv.w;
        }
        const int oc = i / FW;
        ks[i] = acc * (g1[oc] * rsqrtf(v1[oc] + EPS));
    }
    __syncthreads();

    // conv: 1568 units of 8 outputs; xs via LDS float4 reads (proven form)
    const size_t obase = (size_t)b * FC_LEN;
    for (int u = t; u < OC * 49; u += 256) {
        const int oc = u / 49;
        const int w  = (u - oc * 49) * 8;
        float4 q0 = *(const float4*)(xs + w);
        float4 q1 = *(const float4*)(xs + w + 4);
        float4 q2 = *(const float4*)(xs + w + 8);
        float4 q3 = *(const float4*)(xs + w + 12);
        float x[16] = {q0.x, q0.y, q0.z, q0.w, q1.x, q1.y, q1.z, q1.w,
                       q2.x, q2.y, q2.z, q2.w, q3.x, q3.y, q3.z, q3.w};
        const float c0 = cadd[oc];
        float a[8] = {c0, c0, c0, c0, c0, c0, c0, c0};
        #pragma unroll
        for (int j = 0; j < FW; ++j) {
            const float kj = ks[oc * FW + j];
            #pragma unroll
            for (int p = 0; p < 8; ++p) a[p] += x[j + p] * kj;
        }
        bf16x8 o;
        #pragma unroll
        for (int p = 0; p < 8; ++p) o[p] = (__bf16)a[p];
        *(bf16x8*)(flat + obase + oc * W_OUT + w) = o;   // 16B aligned, coalesced
    }
}

// ============ kernel 2: async MFMA GEMM (R7-exact: BK=32, XOR swizzle, split-K 8) ============
__global__ __launch_bounds__(256, 4)
void gemm_async(const __bf16* __restrict__ A, const __bf16* __restrict__ B,
                float* __restrict__ Hpart)
{
    __shared__ __align__(16) __bf16 Asm[TM * BK];   // 8 KB
    __shared__ __align__(16) __bf16 Bsm[TN * BK];   // 8 KB

    const int tid  = threadIdx.x;
    const int wave = tid >> 6;
    const int lane = tid & 63;
    const int m0 = blockIdx.x * TM;
    const int n0 = blockIdx.y * TN;
    const size_t kbase = (size_t)blockIdx.z * KCHA;

    const __bf16* ag[2]; const __bf16* bg[2];
    __bf16* al[2]; __bf16* bl[2];
    #pragma unroll
    for (int c = 0; c < 2; ++c) {
        const int row = c * 64 + wave * 16 + (lane >> 2);
        const int sub = (lane & 3) ^ ((row >> 1) & 3);          // XOR swizzle
        ag[c] = A + (size_t)(m0 + row) * KDIM + kbase + sub * 8;
        int rg = n0 + row; if (rg > NDIM - 1) rg = NDIM - 1;    // clamp padded rows
        bg[c] = B + (size_t)rg * KDIM + kbase + sub * 8;
        al[c] = Asm + c * 2048 + wave * 512;                    // wave-uniform LDS base
        bl[c] = Bsm + c * 2048 + wave * 512;
    }

    const int quad = lane >> 4;
    const int mrow = lane & 15;
    const int wm = wave >> 1, wn = wave & 1;   // 2x2 wave grid, 64x64 per wave
    const __bf16* afr[4]; const __bf16* bfr[4];
    #pragma unroll
    for (int t = 0; t < 4; ++t) {
        const int ra = wm * 64 + t * 16 + mrow;
        const int rb = wn * 64 + t * 16 + mrow;
        afr[t] = Asm + ra * BK + ((quad ^ ((ra >> 1) & 3)) * 8);
        bfr[t] = Bsm + rb * BK + ((quad ^ ((rb >> 1) & 3)) * 8);
    }

    f32x4 acc[4][4];
    #pragma unroll
    for (int i = 0; i < 4; ++i)
        #pragma unroll
        for (int j = 0; j < 4; ++j) acc[i][j] = (f32x4){0.f, 0.f, 0.f, 0.f};

    for (int it = 0; it < KITA; ++it) {
        gld_lds16(ag[0], al[0]);
        gld_lds16(ag[1], al[1]);
        gld_lds16(bg[0], bl[0]);
        gld_lds16(bg[1], bl[1]);
        ag[0] += BK; ag[1] += BK; bg[0] += BK; bg[1] += BK;
        __syncthreads();

        bf16x8 av[4], bv[4];
        #pragma unroll
        for (int t = 0; t < 4; ++t) av[t] = *(const bf16x8*)afr[t];
        #pragma unroll
        for (int t = 0; t < 4; ++t) bv[t] = *(const bf16x8*)bfr[t];
        #pragma unroll
        for (int i = 0; i < 4; ++i)
            #pragma unroll
            for (int j = 0; j < 4; ++j)
                acc[i][j] = __builtin_amdgcn_mfma_f32_16x16x32_bf16(av[i], bv[j], acc[i][j], 0, 0, 0);
        __syncthreads();
    }

    // epilogue: C/D layout col=lane&15, row=(lane>>4)*4+reg  [m89]
    float* Hp = Hpart + (size_t)blockIdx.z * BATCH * NDIM;
    #pragma unroll
    for (int i = 0; i < 4; ++i) {
        const int rbase = m0 + wm * 64 + i * 16 + quad * 4;
        #pragma unroll
        for (int j = 0; j < 4; ++j) {
            const int col = n0 + wn * 64 + j * 16 + mrow;
            if (col < NDIM) {
                #pragma unroll
                for (int r = 0; r < 4; ++r)
                    Hp[(size_t)(rbase + r) * NDIM + col] = acc[i][j][r];
            }
        }
    }
}

// ============ kernel 2b: proven fallback (VGPR staging, fp32 B, split-K 4, BK=32) ============
__global__ __launch_bounds__(256, 2)
void gemm_bt(const __bf16* __restrict__ Aflat, const float* __restrict__ Bwf,
             float* __restrict__ Hpart)
{
    __shared__ __align__(16) __bf16 Asm[TM * 32];
    __shared__ __align__(16) __bf16 Bsm[TN * 32];

    const int tid  = threadIdx.x;
    const int wave = tid >> 6;
    const int lane = tid & 63;
    const int m0 = blockIdx.x * TM;
    const int n0 = blockIdx.y * TN;
    const size_t kbase = (size_t)blockIdx.z * (KDIM / 4);

    const int row0 = tid >> 2, sub = tid & 3;
    const int row1 = 64 + row0;
    const __bf16* ag0 = Aflat + (size_t)(m0 + row0) * KDIM + kbase + sub * 8;
    const __bf16* ag1 = Aflat + (size_t)(m0 + row1) * KDIM + kbase + sub * 8;
    int rg0 = n0 + row0; if (rg0 > NDIM - 1) rg0 = NDIM - 1;
    int rg1 = n0 + row1; if (rg1 > NDIM - 1) rg1 = NDIM - 1;
    const float* bg0 = Bwf + (size_t)rg0 * KDIM + kbase + sub * 8;
    const float* bg1 = Bwf + (size_t)rg1 * KDIM + kbase + sub * 8;
    __bf16* la0 = Asm + tid * 8;
    __bf16* la1 = Asm + 2048 + tid * 8;
    __bf16* lb0 = Bsm + tid * 8;
    __bf16* lb1 = Bsm + 2048 + tid * 8;

    const int quad = lane >> 4;
    const int mrow = lane & 15;
    const int wm = wave >> 1, wn = wave & 1;
    const __bf16* afr[4]; const __bf16* bfr[4];
    #pragma unroll
    for (int t = 0; t < 4; ++t) {
        afr[t] = Asm + (wm * 64 + t * 16 + mrow) * 32 + quad * 8;
        bfr[t] = Bsm + (wn * 64 + t * 16 + mrow) * 32 + quad * 8;
    }

    f32x4 acc[4][4];
    #pragma unroll
    for (int i = 0; i < 4; ++i)
        #pragma unroll
        for (int j = 0; j < 4; ++j) acc[i][j] = (f32x4){0.f, 0.f, 0.f, 0.f};

    for (int it = 0; it < (KDIM / 4) / 32; ++it) {
        bf16x8 ra0 = *(const bf16x8*)ag0;
        bf16x8 ra1 = *(const bf16x8*)ag1;
        float4 b0a = *(const float4*)bg0;
        float4 b0b = *(const float4*)(bg0 + 4);
        float4 b1a = *(const float4*)bg1;
        float4 b1b = *(const float4*)(bg1 + 4);
        ag0 += 32; ag1 += 32; bg0 += 32; bg1 += 32;

        bf16x8 rb0, rb1;
        rb0[0] = (__bf16)b0a.x; rb0[1] = (__bf16)b0a.y; rb0[2] = (__bf16)b0a.z; rb0[3] = (__bf16)b0a.w;
        rb0[4] = (__bf16)b0b.x; rb0[5] = (__bf16)b0b.y; rb0[6] = (__bf16)b0b.z; rb0[7] = (__bf16)b0b.w;
        rb1[0] = (__bf16)b1a.x; rb1[1] = (__bf16)b1a.y; rb1[2] = (__bf16)b1a.z; rb1[3] = (__bf16)b1a.w;
        rb1[4] = (__bf16)b1b.x; rb1[5] = (__bf16)b1b.y; rb1[6] = (__bf16)b1b.z; rb1[7] = (__bf16)b1b.w;

        __syncthreads();
        *(bf16x8*)la0 = ra0;
        *(bf16x8*)la1 = ra1;
        *(bf16x8*)lb0 = rb0;
        *(bf16x8*)lb1 = rb1;
        __syncthreads();

        bf16x8 av[4], bv[4];
        #pragma unroll
        for (int t = 0; t < 4; ++t) av[t] = *(const bf16x8*)afr[t];
        #pragma unroll
        for (int t = 0; t < 4; ++t) bv[t] = *(const bf16x8*)bfr[t];
        #pragma unroll
        for (int i = 0; i < 4; ++i)
            #pragma unroll
            for (int j = 0; j < 4; ++j)
                acc[i][j] = __builtin_amdgcn_mfma_f32_16x16x32_bf16(av[i], bv[j], acc[i][j], 0, 0, 0);
    }

    float* Hp = Hpart + (size_t)blockIdx.z * BATCH * NDIM;
    #pragma unroll
    for (int i = 0; i < 4; ++i) {
        const int rbase = m0 + wm * 64 + i * 16 + quad * 4;
        #pragma unroll
        for (int j = 0; j < 4; ++j) {
            const int col = n0 + wn * 64 + j * 16 + mrow;
            if (col < NDIM) {
                #pragma unroll
                for (int r = 0; r < 4; ++r)
                    Hp[(size_t)(rbase + r) * NDIM + col] = acc[i][j][r];
            }
        }
    }
}

// ============ kernel 3: sum partials + fc_b + bn2 + fc2 dot + tanh + bias ============
__global__ __launch_bounds__(256)
void finalize(const float* __restrict__ Hpart, int sk,
              const float* __restrict__ fcb,
              const float* __restrict__ g2, const float* __restrict__ b2,
              const float* __restrict__ m2, const float* __restrict__ v2,
              const float* __restrict__ fc2w, const float* __restrict__ fc2b,
              const float* __restrict__ bias,
              float* __restrict__ out)
{
    const int wave = threadIdx.x >> 6, lane = threadIdx.x & 63;
    const int e = blockIdx.x * 4 + wave;

    float acc = 0.f;
    for (int o = lane; o < NDIM; o += 64) {
        float hv = 0.f;
        for (int z = 0; z < sk; ++z)
            hv += Hpart[(size_t)z * BATCH * NDIM + (size_t)e * NDIM + o];
        hv += fcb[o];
        const float s2 = g2[o] * rsqrtf(v2[o] + EPS);
        const float hb = (hv - m2[o]) * s2 + b2[o];
        acc += hb * fc2w[o];
    }
    #pragma unroll
    for (int off = 32; off > 0; off >>= 1) acc += __shfl_down(acc, off);
    if (lane == 0)
        out[e] = tanhf(acc + fc2b[0]) + bias[0];
}

extern "C" void kernel_launch(void* const* d_in, const int* in_sizes, int n_in,
                              void* d_out, int out_size, void* d_ws, size_t ws_size,
                              hipStream_t stream)
{
    const int*   e1i  = (const int*)d_in[0];
    const int*   ri   = (const int*)d_in[1];
    const int*   e2i  = (const int*)d_in[2];
    const float* E    = (const float*)d_in[3];
    const float* R    = (const float*)d_in[4];
    const float* g0   = (const float*)d_in[5];
    const float* b0   = (const float*)d_in[6];
    const float* m0p  = (const float*)d_in[7];
    const float* v0   = (const float*)d_in[8];
    const float* fc1w = (const float*)d_in[9];
    const float* fc1b = (const float*)d_in[10];
    const float* g1   = (const float*)d_in[11];
    const float* b1   = (const float*)d_in[12];
    const float* m1   = (const float*)d_in[13];
    const float* v1   = (const float*)d_in[14];
    const float* fcw  = (const float*)d_in[15];
    const float* fcb  = (const float*)d_in[16];
    const float* g2   = (const float*)d_in[17];
    const float* b2   = (const float*)d_in[18];
    const float* m2   = (const float*)d_in[19];
    const float* v2   = (const float*)d_in[20];
    const float* fc2w = (const float*)d_in[21];
    const float* fc2b = (const float*)d_in[22];
    const float* bias = (const float*)d_in[23];

    const size_t flat_b = (size_t)BATCH * FC_LEN * 2;   // 102,760,448
    const size_t bw_b   = (size_t)NDIM * KDIM * 2;      //  10,035,200
    const size_t hp_b1  = (size_t)BATCH * NDIM * 4;     //   6,553,600 per split
    const size_t need8  = flat_b + bw_b + SKA * hp_b1;  // ~165.2 MB (proven: R7 ran sk=8)

    __bf16* flat = (__bf16*)d_ws;

    if (ws_size >= need8) {
        __bf16* Bw    = (__bf16*)((char*)d_ws + flat_b);
        float*  Hpart = (float*)((char*)d_ws + flat_b + bw_b);

        // one dispatch: prep (4096 blocks) + cvt (2450 blocks)
        prep_conv_cvt<<<BATCH + CVT_BLOCKS, 256, 0, stream>>>(
            e1i, ri, e2i, E, R, g0, b0, m0p, v0,
            fc1w, fc1b, g1, b1, m1, v1, fcw, flat, Bw);

        dim3 grid(BATCH / TM, (NDIM + TN - 1) / TN, SKA);   // 32 x 4 x 8
        gemm_async<<<grid, 256, 0, stream>>>(flat, Bw, Hpart);

        finalize<<<BATCH / 4, 256, 0, stream>>>(Hpart, SKA, fcb, g2, b2, m2, v2,
                                                fc2w, fc2b, bias, (float*)d_out);
    } else {
        // fallback: prep only (no cvt blocks), fp32-B gemm, split-K 4
        float* Hpart = (float*)((char*)d_ws + flat_b);

        prep_conv_cvt<<<BATCH, 256, 0, stream>>>(
            e1i, ri, e2i, E, R, g0, b0, m0p, v0,
            fc1w, fc1b, g1, b1, m1, v1, fcw, flat, nullptr);

        dim3 grid(BATCH / TM, (NDIM + TN - 1) / TN, 4);
        gemm_bt<<<grid, 256, 0, stream>>>(flat, fcw, Hpart);
        finalize<<<BATCH / 4, 256, 0, stream>>>(Hpart, 4, fcb, g2, b2, m2, v2,
                                                fc2w, fc2b, bias, (float*)d_out);
    }
}